// Round 1
// baseline (78.738 us; speedup 1.0000x reference)
//
#include <hip/hip_runtime.h>
#include <hip/hip_fp16.h>

#define WIDTH   256
#define HEIGHT  256
#define NG      8192
#define TILE_SZ 16
#define MINW    1e-6f
#define BLK     1024
#define NBATCH  (NG / BLK)      // 8
#define NWAVE   (BLK / 64)      // 16
#define NSEG    16              // depth segments (one per wave)
#define PXB     256             // pixels per block (full 16x16 tile)
#define RSZ     512             // gaussians staged per round
#define KC      (-0.72134752044f)   // -0.5 * log2(e)

// Single fused kernel: cull + pack + depth-split composite.
// 1 block per 16x16 tile -> 256 blocks -> 1 block/CU (16 waves, 4/SIMD).
// 16 depth segments x 64 lanes x 4 px/lane (4 consecutive y share one x):
// each staged gaussian read (2x ds_read_b128) + dx/axx/bdx amortize over 4 px.
// __launch_bounds__(1024,4): 128-VGPR budget (the old (1024,8) capped at 64,
// starving the 4-px-state + gated-recompute loop).
__global__ __launch_bounds__(BLK, 4) void raster_kernel(
    const float* __restrict__ pts,    // [N,2]
    const float* __restrict__ icov,   // [N,2,2]
    const float* __restrict__ rad,    // [N]
    const float* __restrict__ cols,   // [N,3]
    const float* __restrict__ opac,   // [N] logits
    float* __restrict__ out)          // [W,H,3]
{
    __shared__ unsigned long long s_ball[NBATCH * NWAVE];   // 1 KB
    __shared__ int s_pfx[NBATCH * NWAVE];                   // 0.5 KB
    __shared__ __align__(16) char s_pool[49152];            // 48 KB
    unsigned short* s_list = (unsigned short*)s_pool;       // 16 KB ordered ids
    float4* s_g = (float4*)(s_pool + 16384);                // 16 KB staged chunk
    float*  s_red = (float*)s_pool;                         // 48 KB (after loop)
    __shared__ float4 s_P4[NSEG][64];                       // 16 KB seg products
    float* s_Pf = (float*)s_P4;                             // [s][px] float view

    const int tid  = threadIdx.x;
    const int lane = tid & 63;
    const int wave = tid >> 6;
    const int seg  = wave;            // 0..15
    const float tx0 = (float)(blockIdx.x * TILE_SZ);
    const float ty0 = (float)(blockIdx.y * TILE_SZ);
    const float tx1 = tx0 + (float)TILE_SZ;
    const float ty1 = ty0 + (float)TILE_SZ;

    // ---- Phase 1: bbox hit test per batch (tile-granular, same as reference)
    unsigned int hitbits = 0;
    #pragma unroll
    for (int b = 0; b < NBATCH; ++b) {
        const int g = b * BLK + tid;
        const float2 p = ((const float2*)pts)[g];
        const float  r = rad[g];
        bool hit = (floorf(p.x - r) <= tx1) & (ceilf(p.x + r) >= tx0)
                 & (floorf(p.y - r) <= ty1) & (ceilf(p.y + r) >= ty0);
        unsigned long long m = __ballot(hit);
        if (lane == 0) s_ball[b * NWAVE + wave] = m;
        if (hit) hitbits |= (1u << b);
    }
    __syncthreads();
    if (wave == 0) {                  // 128-elem inclusive scan in one wave
        int v0 = __popcll(s_ball[lane]);
        int v1 = __popcll(s_ball[64 + lane]);
        #pragma unroll
        for (int d = 1; d < 64; d <<= 1) {
            const int t0 = __shfl_up(v0, d);
            const int t1 = __shfl_up(v1, d);
            if (lane >= d) { v0 += t0; v1 += t1; }
        }
        s_pfx[lane] = v0;
        s_pfx[64 + lane] = v1 + __shfl(v0, 63);
    }
    __syncthreads();
    const int count = s_pfx[127];
    {
        unsigned int hb = hitbits;
        const unsigned long long ltmask = (1ull << lane) - 1ull;
        while (hb) {
            const int b = __ffs(hb) - 1;  hb &= hb - 1;
            const int idx = b * NWAVE + wave;
            const unsigned long long m = s_ball[idx];
            const int bs = idx ? s_pfx[idx - 1] : 0;
            s_list[bs + __popcll(m & ltmask)] = (unsigned short)(b * BLK + tid);
        }
    }
    __syncthreads();

    // ---- Phase 2: 16 depth segments x 64 lanes x 4 px (shared x per lane)
    const int xl = lane >> 2;         // 0..15 (x within tile)
    const int yb = lane & 3;          // 0..3  (y quad)
    const float fx  = tx0 + (float)xl;
    const float fy0 = ty0 + (float)(4 * yb);   // pixels y0..y0+3
    const int pA = xl * 16 + 4 * yb;  // local pixel id (x-major), == 4*lane
    float Tpx = 1.0f;                 // per-pixel T, owner threads (tid<256)
    float acc[3][4];
    #pragma unroll
    for (int c = 0; c < 3; ++c)
        #pragma unroll
        for (int k = 0; k < 4; ++k) acc[c][k] = 0.0f;

    for (int base = 0; base < count; base += RSZ) {
        const int n = min(RSZ, count - base);
        if (tid < n) {                // inline pack
            const int g = s_list[base + tid];
            const float2 p = ((const float2*)pts)[g];
            const float4 ic = ((const float4*)icov)[g];
            const float op = 1.0f / (1.0f + __expf(-opac[g]));
            const __half2 h = __floats2half2_rn(cols[3 * g], cols[3 * g + 1]);
            unsigned rgbits; __builtin_memcpy(&rgbits, &h, 4);
            s_g[tid * 2 + 0] = make_float4(p.x, p.y, KC * ic.x, 2.0f * KC * ic.y);
            s_g[tid * 2 + 1] = make_float4(KC * ic.w, op, __uint_as_float(rgbits),
                                           cols[3 * g + 2]);
        }
        __syncthreads();

        const int L  = (n + NSEG - 1) >> 4;
        const int i0 = seg * L;
        const int i1 = min(i0 + L, n);

        float P[4] = {1.f, 1.f, 1.f, 1.f};
        float l[3][4];
        #pragma unroll
        for (int c = 0; c < 3; ++c)
            #pragma unroll
            for (int k = 0; k < 4; ++k) l[c][k] = 0.0f;

        #pragma unroll 2
        for (int i = i0; i < i1; ++i) {
            const float4 g0 = s_g[i * 2 + 0];
            const float4 g1 = s_g[i * 2 + 1];
            const float dx  = fx - g0.x;               // shared across the 4 px
            const float axx = (g0.z * dx) * dx;
            const float bdx = g0.w * dx;
            const float dy0 = fy0 - g0.y;
            const unsigned rgbits = __float_as_uint(g1.z);
            __half2 h; __builtin_memcpy(&h, &rgbits, 4);
            const float2 rg = __half22float2(h);
            #pragma unroll
            for (int k = 0; k < 4; ++k) {
                const float dyk = dy0 + (float)k;
                const float q = fmaf(dyk, fmaf(g1.x, dyk, bdx), axx);
                const float a = g1.y * __builtin_amdgcn_exp2f(q);
                const float w = P[k] * a;
                l[0][k] = fmaf(w, rg.x, l[0][k]);
                l[1][k] = fmaf(w, rg.y, l[1][k]);
                l[2][k] = fmaf(w, g1.w, l[2][k]);
                P[k] = fmaf(-a, P[k], P[k]);
            }
        }
        // one conflict-free b128 per thread (floats land at s_Pf[seg*256+pA+k])
        s_P4[seg][lane] = make_float4(P[0], P[1], P[2], P[3]);
        __syncthreads();

        // owner threads: in-place exclusive prefix (Tin per segment) over 16 P's
        if (tid < PXB) {
            float run = Tpx;
            #pragma unroll
            for (int s = 0; s < NSEG; ++s) {
                const float Pv = s_Pf[s * PXB + tid];
                s_Pf[s * PXB + tid] = run;    // Tin for segment s
                run *= Pv;
            }
            Tpx = run;
        }
        __syncthreads();

        const float4 Tv = s_P4[seg][lane];    // Tin for this seg, 4 px
        const float Tin[4] = {Tv.x, Tv.y, Tv.z, Tv.w};
        bool gated[4]; bool anyg = false;
        #pragma unroll
        for (int k = 0; k < 4; ++k) {
            const bool alive = (Tin[k] >= MINW);
            gated[k] = alive && (Tin[k] * P[k] < MINW);  // T crossed in this seg
            if (alive && !gated[k]) {
                acc[0][k] = fmaf(Tin[k], l[0][k], acc[0][k]);
                acc[1][k] = fmaf(Tin[k], l[1][k], acc[1][k]);
                acc[2][k] = fmaf(Tin[k], l[2][k], acc[2][k]);
            }
            anyg |= gated[k];
        }
        if (__ballot(anyg) != 0ull) {         // rare: once per pixel lifetime
            float Tl[4] = {Tin[0], Tin[1], Tin[2], Tin[3]};
            for (int i = i0; i < i1; ++i) {
                const float4 g0 = s_g[i * 2 + 0];
                const float4 g1 = s_g[i * 2 + 1];
                const float dx  = fx - g0.x;
                const float axx = (g0.z * dx) * dx;
                const float bdx = g0.w * dx;
                const float dy0 = fy0 - g0.y;
                const unsigned rgbits = __float_as_uint(g1.z);
                __half2 h; __builtin_memcpy(&h, &rgbits, 4);
                const float2 rg = __half22float2(h);
                #pragma unroll
                for (int k = 0; k < 4; ++k) {
                    const float dyk = dy0 + (float)k;
                    const float q = fmaf(dyk, fmaf(g1.x, dyk, bdx), axx);
                    const float a  = g1.y * __builtin_amdgcn_exp2f(q);
                    const float Tn = Tl[k] * (1.0f - a);
                    const float w  = (gated[k] && Tn >= MINW) ? Tl[k] * a : 0.0f;
                    acc[0][k] = fmaf(w, rg.x, acc[0][k]);
                    acc[1][k] = fmaf(w, rg.y, acc[1][k]);
                    acc[2][k] = fmaf(w, g1.w, acc[2][k]);
                    Tl[k] = Tn;
                }
            }
        }
        const bool mydead = (tid < PXB) ? (Tpx < MINW) : true;
        if (__syncthreads_count(mydead) == BLK) break;   // also guards s_g reuse
    }
    // loop always exits via a barrier => s_list/s_g dead, alias as s_red

    // ---- Reduce 16 segment partials per pixel, store this block's 256 px
    {   // 12 consecutive floats per thread -> 3 aligned float4 stores
        float4* dst = (float4*)&s_red[(seg * PXB + pA) * 3];
        dst[0] = make_float4(acc[0][0], acc[1][0], acc[2][0], acc[0][1]);
        dst[1] = make_float4(acc[1][1], acc[2][1], acc[0][2], acc[1][2]);
        dst[2] = make_float4(acc[2][2], acc[0][3], acc[1][3], acc[2][3]);
    }
    __syncthreads();
    if (tid < PXB * 3) {              // 768 threads, one (px,channel) each
        const int p  = tid / 3;
        const int ch = tid - 3 * p;
        float v = 0.0f;
        #pragma unroll
        for (int s = 0; s < NSEG; ++s) v += s_red[(s * PXB + p) * 3 + ch];
        const int x = blockIdx.x * TILE_SZ + (p >> 4);
        const int y = blockIdx.y * TILE_SZ + (p & 15);
        out[(x * HEIGHT + y) * 3 + ch] = v;
    }
}

extern "C" void kernel_launch(void* const* d_in, const int* in_sizes, int n_in,
                              void* d_out, int out_size, void* d_ws, size_t ws_size,
                              hipStream_t stream) {
    const float* pts  = (const float*)d_in[0];
    const float* icov = (const float*)d_in[1];
    const float* rad  = (const float*)d_in[2];
    const float* cols = (const float*)d_in[3];
    const float* opac = (const float*)d_in[4];
    float* out = (float*)d_out;
    dim3 grid(WIDTH / TILE_SZ, HEIGHT / TILE_SZ, 1);   // 1 block per 16x16 tile
    raster_kernel<<<grid, dim3(BLK), 0, stream>>>(pts, icov, rad, cols, opac, out);
}